// Round 4
// baseline (348.168 us; speedup 1.0000x reference)
//
#include <hip/hip_runtime.h>
#include <stdint.h>

// Problem constants (fixed by the reference)
#define BN    8192    // batch
#define DK    256     // dim
#define PN    4096    // pairs
#define MAXP  16      // max partners tracked per row (Poisson(1); P(>16) ~ 1e-15)
#define RANK_ASC 6553 // ascending rank of first kept element (top-1639 = 0.8 quantile)
#define QSTEP 0.02f   // logit quantization step: code = round(5*cos/QSTEP)+128 in [1,255]

typedef float f32x4  __attribute__((ext_vector_type(4)));
typedef int   i32x4  __attribute__((ext_vector_type(4)));

// ------------------------------------------------ parallel bin finder (256 bins)
__device__ __forceinline__ void find_bin_256(const unsigned* hist, int rank,
                                             int* sh, unsigned* wtot) {
  const int tid = threadIdx.x, lane = tid & 63, w = tid >> 6;
  unsigned x = hist[tid];
  unsigned pref = x;
  #pragma unroll
  for (int o = 1; o < 64; o <<= 1) {
    unsigned y = __shfl_up(pref, o);
    if (lane >= o) pref += y;
  }
  if (lane == 63) wtot[w] = pref;
  __syncthreads();
  unsigned woff = 0;
  for (int i = 0; i < w; ++i) woff += wtot[i];
  unsigned incl = pref + woff, excl = incl - x;
  if ((unsigned)rank >= excl && (unsigned)rank < incl) { sh[0] = tid; sh[1] = rank - (int)excl; }
  __syncthreads();
}

__device__ __forceinline__ float block_sum4(float x, float* red4) {
  const int lane = threadIdx.x & 63, w = threadIdx.x >> 6;
  #pragma unroll
  for (int o = 32; o; o >>= 1) x += __shfl_xor(x, o);
  __syncthreads();
  if (lane == 0) red4[w] = x;
  __syncthreads();
  return red4[0] + red4[1] + red4[2] + red4[3];
}

// ---------------- K1: normalize -> int8 (1 row/wave) + pair scatter + first-touch compact ----
__global__ void __launch_bounds__(256) norm_pairs_kernel(
    const float* __restrict__ X, signed char* __restrict__ Ei8,
    const int2* __restrict__ pairs, int* pcount, int* partners,
    int* rowlist, int* cnt) {
  const int tid  = threadIdx.x;
  const int lane = tid & 63;
  const int wib  = tid >> 6;
  const int row  = blockIdx.x * 4 + wib;      // grid 2048 -> rows 0..8191

  float4 x = ((const float4*)(X + (size_t)row * DK))[lane];
  float ss = x.x * x.x + x.y * x.y + x.z * x.z + x.w * x.w;
  #pragma unroll
  for (int o = 32; o; o >>= 1) ss += __shfl_xor(ss, o);
  float inv = 127.0f / fmaxf(sqrtf(ss), 1e-8f);
  int c0 = (int)rintf(inv * x.x);
  int c1 = (int)rintf(inv * x.y);
  int c2 = (int)rintf(inv * x.z);
  int c3 = (int)rintf(inv * x.w);
  unsigned u = (unsigned)(c0 & 255) | ((unsigned)(c1 & 255) << 8)
             | ((unsigned)(c2 & 255) << 16) | ((unsigned)(c3 & 255) << 24);
  ((unsigned*)(Ei8 + (size_t)row * DK))[lane] = u;

  const int p = blockIdx.x * 256 + tid;
  if (p < PN) {
    int2 pr = pairs[p];
    int ix = atomicAdd(&pcount[pr.x], 1);
    if (ix == 0) { int q = atomicAdd(cnt, 1); rowlist[q] = pr.x; }   // first touch
    if (ix < MAXP) partners[pr.x * MAXP + ix] = pr.y;
    int iy = atomicAdd(&pcount[pr.y], 1);
    if (iy == 0) { int q = atomicAdd(cnt, 1); rowlist[q] = pr.y; }
    if (iy < MAXP) partners[pr.y * MAXP + iy] = pr.x;
  }
}

// ---------------- K2: pos (1 pair/wave, int8 dot) ----------------
__global__ void __launch_bounds__(256) pos_kernel(
    const signed char* __restrict__ Ei8, const int2* __restrict__ pairs,
    float* __restrict__ pos) {
  const int tid  = threadIdx.x;
  const int lane = tid & 63;
  const int wib  = tid >> 6;
  const int p    = blockIdx.x * 4 + wib;      // grid 1024 -> pairs 0..4095
  int2 pr = pairs[p];
  int a = ((const int*)(Ei8 + (size_t)pr.x * DK))[lane];
  int b = ((const int*)(Ei8 + (size_t)pr.y * DK))[lane];
  int s = 0;
  #pragma unroll
  for (int j = 0; j < 4; ++j) {
    int va = (int)(signed char)(a >> (8 * j));
    int vb = (int)(signed char)(b >> (8 * j));
    s += va * vb;
  }
  #pragma unroll
  for (int o = 32; o; o >>= 1) s += __shfl_xor(s, o);
  if (lane == 0) pos[p] = __expf((float)s * (5.0f / 16129.0f));
}

// ---------------- K34: FUSED int8 GEMM + row histogram + quantile-sum ----------------
// R3 theory: the 42 MB out4 write -> 40 MB HBM re-fetch between old K3/K4 was
// the structural cost (FETCH_SIZE showed K4 missing cache; the harness's
// 256 MiB fill flushes L2/L3 each iteration). Fuse: each block = 32 compacted
// rows x ALL 8192 cols. A-frags in registers (2 grp x 4 kstep, loaded once);
// B-frags streamed straight from L2-resident Ei8 (16 lanes x 64 contiguous
// k-bytes = 16 full 64B lines per wave-load, no LDS staging). Codes ->
// LDS hist[32][260] (stride 260: 16B-aligned, ==4 mod 32 so the 4 rows of a
// lane-quarter hit different banks). Per-wave barrier-free tail does the exact
// rank-6553 select + weighted sum (same math as find_bin_256: need = cnt_b +
// excl_b - rank). Fragment/acc/mask semantics copied 1:1 from the verified K3/
// K4 pair -> S bit-identical. Predict: 12-18 us total vs K3+K4's 50-70, HBM
// FETCH ~0 for this phase.
__global__ void __launch_bounds__(512, 2) gemm_stats_kernel(
    const signed char* __restrict__ Ei8, const int* __restrict__ rowlist,
    const int* __restrict__ countp, const int* __restrict__ pcount,
    const int* __restrict__ partners, float* __restrict__ S) {
  const int cnt = *countp;
  const int rbase = blockIdx.x * 32;
  if (rbase >= cnt) return;
  __shared__ unsigned hist[32][260];     // 33.3 KB
  __shared__ int plist[32][MAXP + 1];
  __shared__ int npl[32];
  __shared__ int growl[32];
  const int tid = threadIdx.x, lane = tid & 63, w = tid >> 6;
  const int q  = lane >> 4;              // lane quarter 0..3
  const int cl = lane & 15;

  // per-row metadata (threads 0..31 handle one row each)
  if (tid < 32) {
    int rr = rbase + tid;
    int grow = (rr < cnt) ? rowlist[rr] : -1;
    growl[tid] = grow;
    int np = 0;
    if (grow >= 0) {
      np = pcount[grow]; if (np > MAXP) np = MAXP;
      for (int e = 0; e < np; ++e) plist[tid][e] = partners[grow * MAXP + e];
      plist[tid][np] = grow; np++;      // diagonal
    }
    npl[tid] = np;
  }
  for (int i = tid; i < 32 * 260; i += 512) ((unsigned*)hist)[i] = 0;

  // A fragments in registers: lane supplies row (g*16 + cl), k-bytes kb*64+q*16
  i32x4 afr[2][4];
  #pragma unroll
  for (int g = 0; g < 2; ++g) {
    int rr = rbase + g * 16 + cl;
    int grow = (rr < cnt) ? rowlist[rr] : 0;     // safe dummy for invalid rows
    const signed char* ap = Ei8 + (size_t)grow * DK + q * 16;
    #pragma unroll
    for (int kb = 0; kb < 4; ++kb)
      afr[g][kb] = *(const i32x4*)(ap + kb * 64);
  }
  __syncthreads();

  const float SCL = 250.0f / 16129.0f;  // (1/beta)/(127^2) in code units

  for (int c = 0; c < 64; ++c) {
    const int col = c * 128 + w * 16 + cl;     // 8 waves x 16 cols per chunk
    const signed char* bp = Ei8 + (size_t)col * DK + q * 16;
    i32x4 bfr[4];
    #pragma unroll
    for (int kb = 0; kb < 4; ++kb) bfr[kb] = *(const i32x4*)(bp + kb * 64);
    i32x4 acc0 = {0, 0, 0, 0}, acc1 = {0, 0, 0, 0};
    #pragma unroll
    for (int kb = 0; kb < 4; ++kb) {
      acc0 = __builtin_amdgcn_mfma_i32_16x16x64_i8(afr[0][kb], bfr[kb], acc0, 0, 0, 0);
      acc1 = __builtin_amdgcn_mfma_i32_16x16x64_i8(afr[1][kb], bfr[kb], acc1, 0, 0, 0);
    }
    // epilogue: codes + mask + LDS hist atomics
    #pragma unroll
    for (int g = 0; g < 2; ++g) {
      i32x4 a = g ? acc1 : acc0;
      #pragma unroll
      for (int r = 0; r < 4; ++r) {
        const int lrow = g * 16 + q * 4 + r;   // acc row mapping (verified K3 layout)
        int code = (int)fmaf((float)a[r], SCL, 128.5f);
        code = code < 1 ? 1 : (code > 255 ? 255 : code);
        const int np = npl[lrow];
        for (int e = 0; e < np; ++e)
          if (plist[lrow][e] == col) { code = 0; break; }   // masked -> bin 0
        atomicAdd(&hist[lrow][code], 1u);
      }
    }
  }
  __syncthreads();

  // per-wave tail: rows w*4 .. w*4+3, exact rank select + weighted sum
  for (int ri = 0; ri < 4; ++ri) {
    const int lrow = w * 4 + ri;
    const uint4 cv = *(const uint4*)&hist[lrow][lane * 4];   // 4 bins per lane
    const unsigned s0 = cv.x, s01 = s0 + cv.y, s012 = s01 + cv.z;
    const unsigned tot = s012 + cv.w;
    unsigned pref = tot;                      // wave inclusive scan of totals
    #pragma unroll
    for (int o = 1; o < 64; o <<= 1) {
      unsigned y = __shfl_up(pref, o);
      if (lane >= o) pref += y;
    }
    const unsigned wexcl = pref - tot;
    const unsigned e0 = wexcl, e1 = wexcl + s0, e2 = wexcl + s01, e3 = wexcl + s012;
    const unsigned r = RANK_ASC;
    int fi = -1;
    if      (r >= e0 && r < e0 + cv.x) fi = 0;
    else if (r >= e1 && r < e1 + cv.y) fi = 1;
    else if (r >= e2 && r < e2 + cv.z) fi = 2;
    else if (r >= e3 && r < e3 + cv.w) fi = 3;
    const unsigned long long mask = __ballot(fi >= 0);
    if (mask == 0ULL) continue;               // invalid row (grow<0), nothing to write
    const int owner = __ffsll(mask) - 1;
    const int bown = lane * 4 + fi;
    const unsigned eown = (fi == 0) ? e0 : (fi == 1) ? e1 : (fi == 2) ? e2 : e3;
    const unsigned cown = (fi == 0) ? cv.x : (fi == 1) ? cv.y : (fi == 2) ? cv.z : cv.w;
    int needo = (int)(cown + eown - r);       // elements of bin b that are kept
    const int b = __shfl(bown, owner);
    const int need = __shfl(needo, owner);
    float part = 0.f;
    #pragma unroll
    for (int i2 = 0; i2 < 4; ++i2) {
      const int bin = lane * 4 + i2;
      const unsigned cc = (i2 == 0) ? cv.x : (i2 == 1) ? cv.y : (i2 == 2) ? cv.z : cv.w;
      const float val = __expf((float)(bin - 128) * QSTEP);
      if (bin > b)       part += (float)cc * val;
      else if (bin == b) part += (float)need * val;
    }
    #pragma unroll
    for (int o = 32; o; o >>= 1) part += __shfl_xor(part, o);
    if (lane == 0 && growl[lrow] >= 0) S[growl[lrow]] = part;
  }
}

// ---------------- K5: finale ----------------
// Exact radix select of pos rank 819 -> thr; factorized loss:
// log1p(S/p) = logS - logp + p/S - p^2/(2S^2) + O((p/S)^3), p/S <~ 3e-4
// loss = (n*T - 2P*sl + sp*U - 0.5*sp2*V) / (2P)
__global__ void __launch_bounds__(256) finale_kernel(
    const float* __restrict__ pos, const int2* __restrict__ pairs,
    const float* __restrict__ S, float* __restrict__ out) {
  __shared__ uint32_t v[PN];
  __shared__ unsigned hist[256];
  __shared__ int sh[2];
  __shared__ unsigned wtot[4];
  __shared__ float red4[4];
  const int tid = threadIdx.x;
  for (int i = tid; i < PN; i += 256) v[i] = ((const uint32_t*)pos)[i];
  __syncthreads();
  int rank = 819;                 // 0.2 * 4095 exactly
  uint32_t prefix = 0;
  for (int pass = 0; pass < 4; ++pass) {
    const int shift = 24 - pass * 8;
    hist[tid] = 0;
    __syncthreads();
    for (int i = tid; i < PN; i += 256) {
      uint32_t x = v[i];
      bool match = (pass == 0) || ((x >> (shift + 8)) == (prefix >> (shift + 8)));
      if (match) atomicAdd(&hist[(x >> shift) & 255u], 1u);
    }
    __syncthreads();
    find_bin_256(hist, rank, sh, wtot);
    prefix |= ((uint32_t)sh[0]) << shift;
    rank = sh[1];
    __syncthreads();
  }
  float thr; __builtin_memcpy(&thr, &prefix, 4);

  float n = 0.f, sl = 0.f, sp = 0.f, sp2 = 0.f;
  for (int r = tid; r < PN; r += 256) {
    float p; uint32_t b = v[r]; __builtin_memcpy(&p, &b, 4);
    if (p <= thr) { n += 1.f; sl += __logf(p); sp += p; sp2 += p * p; }
  }
  float t = 0.f, u = 0.f, vv = 0.f;
  for (int c = tid; c < PN; c += 256) {
    int2 pr = pairs[c];
    float s1 = S[pr.x], s2 = S[pr.y];
    float i1 = 1.f / s1, i2 = 1.f / s2;
    t += __logf(s1) + __logf(s2);
    u += i1 + i2;
    vv += i1 * i1 + i2 * i2;
  }
  const float N   = block_sum4(n, red4);
  const float SL  = block_sum4(sl, red4);
  const float SP  = block_sum4(sp, red4);
  const float SP2 = block_sum4(sp2, red4);
  const float T   = block_sum4(t, red4);
  const float U   = block_sum4(u, red4);
  const float V   = block_sum4(vv, red4);
  if (tid == 0) {
    double num = (double)N * T - 2.0 * (double)PN * (double)SL
               + (double)SP * U - 0.5 * (double)SP2 * V;
    out[0] = (float)(num / (2.0 * (double)PN));
  }
}

// ---------------------------------------------------------------- launch
extern "C" void kernel_launch(void* const* d_in, const int* in_sizes, int n_in,
                              void* d_out, int out_size, void* d_ws, size_t ws_size,
                              hipStream_t stream) {
  const float* emb  = (const float*)d_in[0];
  const int2* pairs = (const int2*)d_in[1];
  float* out = (float*)d_out;

  // ws layout: [pcnt | rlist | cnt] contiguous -> ONE async memset clears all
  char* w = (char*)d_ws;
  size_t off = 0;
  int*         pcnt  = (int*)(w + off);         off += (size_t)BN * 4;
  int*         rlist = (int*)(w + off);         off += (size_t)BN * 4;
  int*         cnt   = (int*)(w + off);         off += 256;
  signed char* Ei8   = (signed char*)(w + off); off += (size_t)BN * DK;      // 2 MB
  float*       S     = (float*)(w + off);       off += (size_t)BN * 4;
  float*       pos   = (float*)(w + off);       off += (size_t)PN * 4;
  int*         parts = (int*)(w + off);         off += (size_t)BN * MAXP * 4; // 512 KB

  hipMemsetAsync(pcnt, 0, (size_t)BN * 8 + 256, stream);   // pcnt + rlist + cnt
  norm_pairs_kernel<<<BN / 4, 256, 0, stream>>>(emb, Ei8, pairs, pcnt, parts, rlist, cnt);
  pos_kernel<<<PN / 4, 256, 0, stream>>>(Ei8, pairs, pos);
  gemm_stats_kernel<<<BN / 32, 512, 0, stream>>>(Ei8, rlist, cnt, pcnt, parts, S);
  finale_kernel<<<1, 256, 0, stream>>>(pos, pairs, S, out);
}

// Round 5
// 153.134 us; speedup vs baseline: 2.2736x; 2.2736x over previous
//
#include <hip/hip_runtime.h>
#include <stdint.h>

// Problem constants (fixed by the reference)
#define BN    8192    // batch
#define DK    256     // dim
#define PN    4096    // pairs
#define MAXP  16      // max partners tracked per row (Poisson(1); P(>16) ~ 1e-15)
#define RANK_ASC 6553 // ascending rank of first kept element (top-1639 = 0.8 quantile)
#define QSTEP 0.02f   // logit quantization step: code = round(5*cos/QSTEP)+128 in [1,255]

typedef float f32x4  __attribute__((ext_vector_type(4)));
typedef int   i32x4  __attribute__((ext_vector_type(4)));

#define MF(a,b,c) __builtin_amdgcn_mfma_i32_16x16x64_i8(a, b, c, 0, 0, 0)

// ------------------------------------------------ parallel bin finder (256 bins)
__device__ __forceinline__ void find_bin_256(const unsigned* hist, int rank,
                                             int* sh, unsigned* wtot) {
  const int tid = threadIdx.x, lane = tid & 63, w = tid >> 6;
  unsigned x = hist[tid];
  unsigned pref = x;
  #pragma unroll
  for (int o = 1; o < 64; o <<= 1) {
    unsigned y = __shfl_up(pref, o);
    if (lane >= o) pref += y;
  }
  if (lane == 63) wtot[w] = pref;
  __syncthreads();
  unsigned woff = 0;
  for (int i = 0; i < w; ++i) woff += wtot[i];
  unsigned incl = pref + woff, excl = incl - x;
  if ((unsigned)rank >= excl && (unsigned)rank < incl) { sh[0] = tid; sh[1] = rank - (int)excl; }
  __syncthreads();
}

__device__ __forceinline__ float block_sum4(float x, float* red4) {
  const int lane = threadIdx.x & 63, w = threadIdx.x >> 6;
  #pragma unroll
  for (int o = 32; o; o >>= 1) x += __shfl_xor(x, o);
  __syncthreads();
  if (lane == 0) red4[w] = x;
  __syncthreads();
  return red4[0] + red4[1] + red4[2] + red4[3];
}

// ---------------- K1: normalize -> int8 (1 row/wave) + pair scatter + first-touch compact ----
__global__ void __launch_bounds__(256) norm_pairs_kernel(
    const float* __restrict__ X, signed char* __restrict__ Ei8,
    const int2* __restrict__ pairs, int* pcount, int* partners,
    int* rowlist, int* cnt) {
  const int tid  = threadIdx.x;
  const int lane = tid & 63;
  const int wib  = tid >> 6;
  const int row  = blockIdx.x * 4 + wib;      // grid 2048 -> rows 0..8191

  float4 x = ((const float4*)(X + (size_t)row * DK))[lane];
  float ss = x.x * x.x + x.y * x.y + x.z * x.z + x.w * x.w;
  #pragma unroll
  for (int o = 32; o; o >>= 1) ss += __shfl_xor(ss, o);
  float inv = 127.0f / fmaxf(sqrtf(ss), 1e-8f);
  int c0 = (int)rintf(inv * x.x);
  int c1 = (int)rintf(inv * x.y);
  int c2 = (int)rintf(inv * x.z);
  int c3 = (int)rintf(inv * x.w);
  unsigned u = (unsigned)(c0 & 255) | ((unsigned)(c1 & 255) << 8)
             | ((unsigned)(c2 & 255) << 16) | ((unsigned)(c3 & 255) << 24);
  ((unsigned*)(Ei8 + (size_t)row * DK))[lane] = u;

  const int p = blockIdx.x * 256 + tid;
  if (p < PN) {
    int2 pr = pairs[p];
    int ix = atomicAdd(&pcount[pr.x], 1);
    if (ix == 0) { int q = atomicAdd(cnt, 1); rowlist[q] = pr.x; }   // first touch
    if (ix < MAXP) partners[pr.x * MAXP + ix] = pr.y;
    int iy = atomicAdd(&pcount[pr.y], 1);
    if (iy == 0) { int q = atomicAdd(cnt, 1); rowlist[q] = pr.y; }
    if (iy < MAXP) partners[pr.y * MAXP + iy] = pr.x;
  }
}

// ---------------- K2: pos (1 pair/wave, int8 dot) ----------------
__global__ void __launch_bounds__(256) pos_kernel(
    const signed char* __restrict__ Ei8, const int2* __restrict__ pairs,
    float* __restrict__ pos) {
  const int tid  = threadIdx.x;
  const int lane = tid & 63;
  const int wib  = tid >> 6;
  const int p    = blockIdx.x * 4 + wib;      // grid 1024 -> pairs 0..4095
  int2 pr = pairs[p];
  int a = ((const int*)(Ei8 + (size_t)pr.x * DK))[lane];
  int b = ((const int*)(Ei8 + (size_t)pr.y * DK))[lane];
  int s = 0;
  #pragma unroll
  for (int j = 0; j < 4; ++j) {
    int va = (int)(signed char)(a >> (8 * j));
    int vb = (int)(signed char)(b >> (8 * j));
    s += va * vb;
  }
  #pragma unroll
  for (int o = 32; o; o >>= 1) s += __shfl_xor(s, o);
  if (lane == 0) pos[p] = __expf((float)s * (5.0f / 16129.0f));
}

// ---------------- K3: fused int8 GEMM -> per-row code histogram (global merge) ----
// R4 post-mortem: 256-block fusion was latency-bound (1 block/CU, 64 serial
// iters, divergent plist scan ~10k cyc/iter). Fix: 4 column-splits (block =
// 32 rows x 2048 cols, grid 4x256 -> ~648 active = 2.5 blocks/CU), 16 iters,
// register double-buffered B prefetch, and NO masking in the hot loop --
// histogram everything, masked elements are subtracted exactly in row_stats
// (dedupe + identical int8-dot + identical fmaf rounding -> same codes).
// Per-block LDS hist[32][260] (pad: stride==4 mod 32 decorrelates the 4 rows
// of a lane-quarter), then sparse atomic merge into ghist[row][256].
__global__ void __launch_bounds__(512) gemm_hist_kernel(
    const signed char* __restrict__ Ei8, const int* __restrict__ rowlist,
    const int* __restrict__ countp, unsigned* __restrict__ ghist) {
  const int cnt = *countp;
  const int rbase = blockIdx.y * 32;
  if (rbase >= cnt) return;
  __shared__ unsigned hist[32][260];     // 33.3 KB
  const int tid = threadIdx.x, lane = tid & 63, w = tid >> 6;
  const int q  = lane >> 4;              // lane quarter 0..3
  const int cl = lane & 15;

  for (int i = tid; i < 32 * 260; i += 512) ((unsigned*)hist)[i] = 0;

  // A fragments in registers: lane supplies row (g*16 + cl), k-bytes q*16 + kb*64
  i32x4 afr[2][4];
  #pragma unroll
  for (int g = 0; g < 2; ++g) {
    int rr = rbase + g * 16 + cl;
    int grow = (rr < cnt) ? rowlist[rr] : 0;     // dummy row for tail slots
    const signed char* ap = Ei8 + (size_t)grow * DK + q * 16;
    #pragma unroll
    for (int kb = 0; kb < 4; ++kb)
      afr[g][kb] = *(const i32x4*)(ap + kb * 64);
  }
  __syncthreads();

  const float SCL = 250.0f / 16129.0f;  // (1/beta)/(127^2) in code units
  const int colbase = blockIdx.x * 2048 + w * 16 + cl;   // this thread's col seq

  i32x4 b0, b1, b2, b3, n0, n1, n2, n3;
  {
    const signed char* bp = Ei8 + (size_t)colbase * DK + q * 16;
    b0 = *(const i32x4*)(bp);
    b1 = *(const i32x4*)(bp + 64);
    b2 = *(const i32x4*)(bp + 128);
    b3 = *(const i32x4*)(bp + 192);
  }
  for (int c = 0; c < 16; ++c) {
    if (c < 15) {   // prefetch next chunk's B while this chunk computes
      const signed char* bp = Ei8 + (size_t)(colbase + (c + 1) * 128) * DK + q * 16;
      n0 = *(const i32x4*)(bp);
      n1 = *(const i32x4*)(bp + 64);
      n2 = *(const i32x4*)(bp + 128);
      n3 = *(const i32x4*)(bp + 192);
    }
    i32x4 acc0 = {0, 0, 0, 0}, acc1 = {0, 0, 0, 0};
    acc0 = MF(afr[0][0], b0, acc0); acc1 = MF(afr[1][0], b0, acc1);
    acc0 = MF(afr[0][1], b1, acc0); acc1 = MF(afr[1][1], b1, acc1);
    acc0 = MF(afr[0][2], b2, acc0); acc1 = MF(afr[1][2], b2, acc1);
    acc0 = MF(afr[0][3], b3, acc0); acc1 = MF(afr[1][3], b3, acc1);
    // epilogue: quantize + LDS hist (no masking here -- subtracted in K4)
    #pragma unroll
    for (int r = 0; r < 4; ++r) {
      int v0 = (int)fmaf((float)acc0[r], SCL, 128.5f);
      v0 = v0 < 1 ? 1 : (v0 > 255 ? 255 : v0);
      atomicAdd(&hist[q * 4 + r][v0], 1u);
      int v1 = (int)fmaf((float)acc1[r], SCL, 128.5f);
      v1 = v1 < 1 ? 1 : (v1 > 255 ? 255 : v1);
      atomicAdd(&hist[16 + q * 4 + r][v1], 1u);
    }
    b0 = n0; b1 = n1; b2 = n2; b3 = n3;
  }
  __syncthreads();

  // sparse merge: ~60 occupied bins/row -> skip zeros
  for (int i = tid; i < 32 * 256; i += 512) {
    const int lrow = i >> 8, bin = i & 255;
    unsigned v = hist[lrow][bin];
    if (v) atomicAdd(&ghist[(size_t)(rbase + lrow) * 256 + bin], v);
  }
}

// ---------------- K4: per-row stats from global histogram ----------------
// One block per 4 compacted rows; wave w owns row g*4+w. Load the 256-bin row
// (4 bins/lane), recompute masked codes exactly (dedupe: subtraction is not
// idempotent -- self-pairs/dup pairs/reverse-dups all collapse), decrement
// those bins and move the count to bin 0 => identical semantics to the
// verified byte-clear path. Then the R4-verified wave select + weighted sum.
__global__ void __launch_bounds__(256) row_stats_kernel(
    const unsigned* __restrict__ ghist, const signed char* __restrict__ Ei8,
    const int* __restrict__ rowlist, const int* __restrict__ countp,
    const int* __restrict__ pcount, const int* __restrict__ partners,
    float* __restrict__ S) {
  const int cnt = *countp;
  const int g = blockIdx.x;
  if (g * 4 >= cnt) return;
  __shared__ int plist[4][MAXP + 1];
  __shared__ int npl[4];
  __shared__ int growl[4];
  const int tid = threadIdx.x, lane = tid & 63, w = tid >> 6;

  if (tid < 4) {
    int rr = g * 4 + tid;
    int grow = (rr < cnt) ? rowlist[rr] : -1;
    growl[tid] = grow;
    int np = 0;
    if (grow >= 0) {
      np = pcount[grow]; if (np > MAXP) np = MAXP;
      for (int e = 0; e < np; ++e) plist[tid][e] = partners[grow * MAXP + e];
      plist[tid][np] = grow; np++;      // diagonal
    }
    npl[tid] = np;
  }
  __syncthreads();

  const int rr = g * 4 + w;
  const int grow = growl[w];
  if (grow < 0) return;                  // wave-uniform exit

  uint4 cv = *(const uint4*)&ghist[(size_t)rr * 256 + lane * 4];

  // subtract masked elements (recompute exact GEMM codes), move to bin 0
  const int arow = ((const int*)(Ei8 + (size_t)grow * DK))[lane];
  const int np = npl[w];
  unsigned nm = 0;
  for (int e = 0; e < np; ++e) {
    const int col = plist[w][e];
    bool dup = false;
    for (int f = 0; f < e; ++f) if (plist[w][f] == col) { dup = true; break; }
    if (dup) continue;
    const int bcol = ((const int*)(Ei8 + (size_t)col * DK))[lane];
    int s = 0;
    #pragma unroll
    for (int j = 0; j < 4; ++j) {
      int va = (int)(signed char)(arow >> (8 * j));
      int vb = (int)(signed char)(bcol >> (8 * j));
      s += va * vb;
    }
    #pragma unroll
    for (int o = 32; o; o >>= 1) s += __shfl_xor(s, o);
    int code = (int)fmaf((float)s, 250.0f / 16129.0f, 128.5f);
    code = code < 1 ? 1 : (code > 255 ? 255 : code);
    nm++;
    if ((code >> 2) == lane) {
      switch (code & 3) {
        case 0: cv.x -= 1u; break;
        case 1: cv.y -= 1u; break;
        case 2: cv.z -= 1u; break;
        default: cv.w -= 1u; break;
      }
    }
  }
  if (lane == 0) cv.x += nm;

  // wave-level exact rank select + weighted sum (verified in R4)
  const unsigned s0 = cv.x, s01 = s0 + cv.y, s012 = s01 + cv.z;
  const unsigned tot = s012 + cv.w;
  unsigned pref = tot;
  #pragma unroll
  for (int o = 1; o < 64; o <<= 1) {
    unsigned y = __shfl_up(pref, o);
    if (lane >= o) pref += y;
  }
  const unsigned wexcl = pref - tot;
  const unsigned e0 = wexcl, e1 = wexcl + s0, e2 = wexcl + s01, e3 = wexcl + s012;
  const unsigned r = RANK_ASC;
  int fi = -1;
  if      (r >= e0 && r < e0 + cv.x) fi = 0;
  else if (r >= e1 && r < e1 + cv.y) fi = 1;
  else if (r >= e2 && r < e2 + cv.z) fi = 2;
  else if (r >= e3 && r < e3 + cv.w) fi = 3;
  const unsigned long long mask = __ballot(fi >= 0);
  if (mask == 0ULL) return;
  const int owner = __ffsll(mask) - 1;
  const int bown = lane * 4 + fi;
  const unsigned eown = (fi == 0) ? e0 : (fi == 1) ? e1 : (fi == 2) ? e2 : e3;
  const unsigned cown = (fi == 0) ? cv.x : (fi == 1) ? cv.y : (fi == 2) ? cv.z : cv.w;
  int needo = (int)(cown + eown - r);
  const int b = __shfl(bown, owner);
  const int need = __shfl(needo, owner);
  float part = 0.f;
  #pragma unroll
  for (int i2 = 0; i2 < 4; ++i2) {
    const int bin = lane * 4 + i2;
    const unsigned cc = (i2 == 0) ? cv.x : (i2 == 1) ? cv.y : (i2 == 2) ? cv.z : cv.w;
    const float val = __expf((float)(bin - 128) * QSTEP);
    if (bin > b)       part += (float)cc * val;
    else if (bin == b) part += (float)need * val;
  }
  #pragma unroll
  for (int o = 32; o; o >>= 1) part += __shfl_xor(part, o);
  if (lane == 0) S[grow] = part;
}

// ---------------- K5: finale ----------------
// Exact radix select of pos rank 819 -> thr; factorized loss:
// log1p(S/p) = logS - logp + p/S - p^2/(2S^2) + O((p/S)^3), p/S <~ 3e-4
// loss = (n*T - 2P*sl + sp*U - 0.5*sp2*V) / (2P)
__global__ void __launch_bounds__(256) finale_kernel(
    const float* __restrict__ pos, const int2* __restrict__ pairs,
    const float* __restrict__ S, float* __restrict__ out) {
  __shared__ uint32_t v[PN];
  __shared__ unsigned hist[256];
  __shared__ int sh[2];
  __shared__ unsigned wtot[4];
  __shared__ float red4[4];
  const int tid = threadIdx.x;
  for (int i = tid; i < PN; i += 256) v[i] = ((const uint32_t*)pos)[i];
  __syncthreads();
  int rank = 819;                 // 0.2 * 4095 exactly
  uint32_t prefix = 0;
  for (int pass = 0; pass < 4; ++pass) {
    const int shift = 24 - pass * 8;
    hist[tid] = 0;
    __syncthreads();
    for (int i = tid; i < PN; i += 256) {
      uint32_t x = v[i];
      bool match = (pass == 0) || ((x >> (shift + 8)) == (prefix >> (shift + 8)));
      if (match) atomicAdd(&hist[(x >> shift) & 255u], 1u);
    }
    __syncthreads();
    find_bin_256(hist, rank, sh, wtot);
    prefix |= ((uint32_t)sh[0]) << shift;
    rank = sh[1];
    __syncthreads();
  }
  float thr; __builtin_memcpy(&thr, &prefix, 4);

  float n = 0.f, sl = 0.f, sp = 0.f, sp2 = 0.f;
  for (int r = tid; r < PN; r += 256) {
    float p; uint32_t b = v[r]; __builtin_memcpy(&p, &b, 4);
    if (p <= thr) { n += 1.f; sl += __logf(p); sp += p; sp2 += p * p; }
  }
  float t = 0.f, u = 0.f, vv = 0.f;
  for (int c = tid; c < PN; c += 256) {
    int2 pr = pairs[c];
    float s1 = S[pr.x], s2 = S[pr.y];
    float i1 = 1.f / s1, i2 = 1.f / s2;
    t += __logf(s1) + __logf(s2);
    u += i1 + i2;
    vv += i1 * i1 + i2 * i2;
  }
  const float N   = block_sum4(n, red4);
  const float SL  = block_sum4(sl, red4);
  const float SP  = block_sum4(sp, red4);
  const float SP2 = block_sum4(sp2, red4);
  const float T   = block_sum4(t, red4);
  const float U   = block_sum4(u, red4);
  const float V   = block_sum4(vv, red4);
  if (tid == 0) {
    double num = (double)N * T - 2.0 * (double)PN * (double)SL
               + (double)SP * U - 0.5 * (double)SP2 * V;
    out[0] = (float)(num / (2.0 * (double)PN));
  }
}

// ---------------------------------------------------------------- launch
extern "C" void kernel_launch(void* const* d_in, const int* in_sizes, int n_in,
                              void* d_out, int out_size, void* d_ws, size_t ws_size,
                              hipStream_t stream) {
  const float* emb  = (const float*)d_in[0];
  const int2* pairs = (const int2*)d_in[1];
  float* out = (float*)d_out;

  // ws layout: [pcnt | rlist | cnt | ghist] contiguous -> ONE async memset clears all
  char* w = (char*)d_ws;
  size_t off = 0;
  int*         pcnt  = (int*)(w + off);         off += (size_t)BN * 4;
  int*         rlist = (int*)(w + off);         off += (size_t)BN * 4;
  int*         cnt   = (int*)(w + off);         off += 256;
  unsigned*    ghist = (unsigned*)(w + off);    off += (size_t)BN * 256 * 4;  // 8 MB
  signed char* Ei8   = (signed char*)(w + off); off += (size_t)BN * DK;       // 2 MB
  float*       S     = (float*)(w + off);       off += (size_t)BN * 4;
  float*       pos   = (float*)(w + off);       off += (size_t)PN * 4;
  int*         parts = (int*)(w + off);         off += (size_t)BN * MAXP * 4; // 512 KB

  hipMemsetAsync(pcnt, 0, (size_t)BN * 8 + 256 + (size_t)BN * 1024, stream);
  norm_pairs_kernel<<<BN / 4, 256, 0, stream>>>(emb, Ei8, pairs, pcnt, parts, rlist, cnt);
  pos_kernel<<<PN / 4, 256, 0, stream>>>(Ei8, pairs, pos);
  gemm_hist_kernel<<<dim3(4, BN / 32), 512, 0, stream>>>(Ei8, rlist, cnt, ghist);
  row_stats_kernel<<<BN / 4, 256, 0, stream>>>(ghist, Ei8, rlist, cnt, pcnt, parts, S);
  finale_kernel<<<1, 256, 0, stream>>>(pos, pairs, S, out);
}